// Round 4
// baseline (222.545 us; speedup 1.0000x reference)
//
#include <hip/hip_runtime.h>
#include <hip/hip_bf16.h>

// Problem: B=4096, L=50, D=64, E=128, CAT=384, U=256, V=100000
// Dtypes per reference: ALL float tensors fp32 (float*), ids/mask int32,
// out fp32 [B,E]. (Rounds 1-3 NaN == fp32 buffers misread as bf16.)
//
// Factored algebra: h = relu(q·W_q + k·W_k + (q*k)·W_qk + b_hide)
//   qvec[u] = q·W_q[:,u] + b_hide[u]   (fp32 VALU, per-block)
//   GEMM per b: [64pad x 256] x [256 x 256], A=[K | K*q] bf16, B=[W_k;W_qk] bf16
// scores = (h·W_out + b_out) * mask ; out[b] = scores · K   (fp32)
//
// W^T lives in a static __device__ global (no d_ws assumptions).

#define L_SEQ 50
#define LP    64
#define D_EMB 64
#define E_DIM 128
#define U_DIM 256
#define CATK  384
#define V_SZ  100000
#define KSTR  136   // LDS row stride (bf16 elems): 16B-aligned rows

typedef __bf16 bf16x4 __attribute__((ext_vector_type(4)));
typedef __bf16 bf16x8 __attribute__((ext_vector_type(8)));
typedef float  f32x4  __attribute__((ext_vector_type(4)));

// module-owned: g_Wt[n][kk] = bf16(W_hide[kk][n]), 256x384 bf16 = 192 KB
__device__ __bf16 g_Wt[U_DIM * CATK];

// ---- prep: transpose+cast W_hide fp32 [384][256] -> g_Wt bf16 [256][384] ----
__global__ __launch_bounds__(256) void wt_transpose_kernel(
    const float* __restrict__ W_hide) {
  __shared__ __bf16 tile[64][72];
  const int bc = blockIdx.x % 6, bu = blockIdx.x / 6;   // c-tile 0..5, u-tile 0..3
  const int tx = threadIdx.x & 63, ty = threadIdx.x >> 6;
  for (int i = 0; i < 64; i += 4) {
    int c = bc * 64 + i + ty;          // 0..383
    int u = bu * 64 + tx;              // 0..255
    tile[i + ty][tx] = (__bf16)W_hide[c * 256 + u];   // coalesced fp32 read
  }
  __syncthreads();
  for (int i = 0; i < 64; i += 4) {
    int u = bu * 64 + i + ty;
    int c = bc * 64 + tx;
    g_Wt[u * CATK + c] = tile[tx][i + ty];
  }
}

// ---- main: one block (4 waves) per b ----
__global__ __launch_bounds__(256) void din_main_kernel(
    const int* __restrict__ qid_item, const int* __restrict__ qid_cate,
    const int* __restrict__ seq_item, const int* __restrict__ seq_cate,
    const int* __restrict__ mask,
    const float* __restrict__ emb_item,
    const float* __restrict__ emb_cate,
    const float* __restrict__ b_hide,  // [256]
    const float* __restrict__ W_out,   // [256]
    const float* __restrict__ b_out,   // [1]
    float* __restrict__ out) {
  __shared__ alignas(16) __bf16 Kb[LP * KSTR];   // bf16(K)
  __shared__ alignas(16) __bf16 A2[LP * KSTR];   // bf16(K*q)
  __shared__ alignas(16) float qrowf[E_DIM];     // fp32 q
  __shared__ float qv_s[U_DIM];
  __shared__ float mask_f[LP];
  __shared__ float scpart[4][LP];
  __shared__ float scores[LP];

  const int b = blockIdx.x;
  const int t = threadIdx.x;
  const int r = t >> 2, q4 = t & 3;
  const int col0 = q4 * 32;   // this thread's 32 columns of [item|cate]

  // ---- phase 1: gather K rows (fp32) into regs, cast to LDS bf16 ----
  float4 kv[8];
  if (r < L_SEQ) {
    int id = (q4 < 2) ? seq_item[b * L_SEQ + r] : seq_cate[b * L_SEQ + r];
    if ((unsigned)id >= (unsigned)V_SZ) id = 0;   // insurance
    const float4* s4 = (const float4*)(((q4 < 2) ? emb_item : emb_cate)
                                       + (size_t)id * D_EMB + (q4 & 1) * 32);
#pragma unroll
    for (int i = 0; i < 8; ++i) kv[i] = s4[i];
  } else {
#pragma unroll
    for (int i = 0; i < 8; ++i) kv[i] = make_float4(0.f, 0.f, 0.f, 0.f);
  }
#pragma unroll
  for (int i = 0; i < 8; ++i) {
    bf16x4 h4 = {(__bf16)kv[i].x, (__bf16)kv[i].y, (__bf16)kv[i].z, (__bf16)kv[i].w};
    *(bf16x4*)&Kb[r * KSTR + col0 + i * 4] = h4;   // 8B store, aligned
  }
  if (t < 4) {   // q row: 4 threads x 32 floats
    int id = (t < 2) ? qid_item[b] : qid_cate[b];
    if ((unsigned)id >= (unsigned)V_SZ) id = 0;
    const float4* s4 = (const float4*)(((t < 2) ? emb_item : emb_cate)
                                       + (size_t)id * D_EMB + (t & 1) * 32);
    float4* d4 = (float4*)&qrowf[t * 32];
#pragma unroll
    for (int i = 0; i < 8; ++i) d4[i] = s4[i];
  }
  if (t < LP) mask_f[t] = (t < L_SEQ && mask[b * L_SEQ + t] != 0) ? 1.0f : 0.0f;
  __syncthreads();

  // ---- phase 2: A2 = bf16(K * q) from fp32 regs (single rounding) ----
#pragma unroll
  for (int i = 0; i < 8; ++i) {
    const float* qp = &qrowf[col0 + i * 4];
    bf16x4 h4 = {(__bf16)(kv[i].x * qp[0]), (__bf16)(kv[i].y * qp[1]),
                 (__bf16)(kv[i].z * qp[2]), (__bf16)(kv[i].w * qp[3])};
    *(bf16x4*)&A2[r * KSTR + col0 + i * 4] = h4;
  }
  __syncthreads();

  // ---- phase 3a: qv_s[u=t] = b_hide[u] + sum_c q[c]*W_q[c][u] (fp32 acc) ----
  {
    float acc_q = b_hide[t];
#pragma unroll
    for (int c8 = 0; c8 < 16; ++c8) {
      bf16x8 w = *(const bf16x8*)&g_Wt[t * CATK + c8 * 8];   // W_q^T slice
#pragma unroll
      for (int j = 0; j < 8; ++j)
        acc_q += qrowf[c8 * 8 + j] * (float)w[j];
    }
    qv_s[t] = acc_q;
  }

  // ---- phase 3b: MFMA. M=64 (4 tiles), N=64/wave (4 tiles), K=256 (8 steps) ----
  const int wave = t >> 6, lane = t & 63;
  const int m = lane & 15, quad = lane >> 4;
  f32x4 acc[4][4];
#pragma unroll
  for (int mt = 0; mt < 4; ++mt)
#pragma unroll
    for (int nt = 0; nt < 4; ++nt) acc[mt][nt] = (f32x4){0.f, 0.f, 0.f, 0.f};

#pragma unroll
  for (int s = 0; s < 8; ++s) {
    const __bf16* Ab = (s < 4) ? Kb : A2;
    const int klocal = (s & 3) * 32 + quad * 8;
    const int kglob  = s * 32 + quad * 8;       // k in [0,256) of [W_k;W_qk]
    bf16x8 afr[4], bfr[4];
#pragma unroll
    for (int mt = 0; mt < 4; ++mt)
      afr[mt] = *(const bf16x8*)&Ab[(mt * 16 + m) * KSTR + klocal];
#pragma unroll
    for (int nt = 0; nt < 4; ++nt) {
      int n = wave * 64 + nt * 16 + m;
      bfr[nt] = *(const bf16x8*)&g_Wt[n * CATK + 128 + kglob];  // skip W_q slice
    }
#pragma unroll
    for (int mt = 0; mt < 4; ++mt)
#pragma unroll
      for (int nt = 0; nt < 4; ++nt)
        acc[mt][nt] = __builtin_amdgcn_mfma_f32_16x16x32_bf16(
            afr[mt], bfr[nt], acc[mt][nt], 0, 0, 0);
  }
  __syncthreads();   // qv_s ready for cross-thread reads

  // ---- epilogue: h = relu(acc + qv_s[n]); partial score = h·W_out ----
  float qv[4], wo[4];
#pragma unroll
  for (int nt = 0; nt < 4; ++nt) {
    int n = wave * 64 + nt * 16 + m;
    qv[nt] = qv_s[n];
    wo[nt] = W_out[n];
  }
  float part[16];   // rows mt*16 + quad*4 + rg
#pragma unroll
  for (int mt = 0; mt < 4; ++mt)
#pragma unroll
    for (int rg = 0; rg < 4; ++rg) {
      float sum = 0.f;
#pragma unroll
      for (int nt = 0; nt < 4; ++nt) {
        float h = acc[mt][nt][rg] + qv[nt];
        h = fmaxf(h, 0.f);
        sum += h * wo[nt];
      }
      part[mt * 4 + rg] = sum;
    }
  // reduce across the 16 lanes (m=0..15) holding the same rows
#pragma unroll
  for (int off = 1; off < 16; off <<= 1)
#pragma unroll
    for (int i = 0; i < 16; ++i)
      part[i] += __shfl_xor(part[i], off, 64);
  if (m == 0) {
#pragma unroll
    for (int mt = 0; mt < 4; ++mt)
#pragma unroll
      for (int rg = 0; rg < 4; ++rg)
        scpart[wave][mt * 16 + quad * 4 + rg] = part[mt * 4 + rg];
  }
  __syncthreads();
  if (t < LP) {
    float s = scpart[0][t] + scpart[1][t] + scpart[2][t] + scpart[3][t]
            + b_out[0];
    scores[t] = s * mask_f[t];
  }
  __syncthreads();
  // out[b][e] = sum_l scores[l] * K[l][e]   (fp32 out)
  if (t < E_DIM) {
    float o = 0.f;
    for (int l = 0; l < L_SEQ; ++l)
      o += scores[l] * (float)Kb[l * KSTR + t];
    out[(size_t)b * E_DIM + t] = o;
  }
}

extern "C" void kernel_launch(void* const* d_in, const int* in_sizes, int n_in,
                              void* d_out, int out_size, void* d_ws, size_t ws_size,
                              hipStream_t stream) {
  const int* qid_item = (const int*)d_in[0];
  const int* qid_cate = (const int*)d_in[1];
  const int* seq_item = (const int*)d_in[2];
  const int* seq_cate = (const int*)d_in[3];
  const int* mask     = (const int*)d_in[4];
  const float* emb_item = (const float*)d_in[5];
  const float* emb_cate = (const float*)d_in[6];
  const float* W_hide   = (const float*)d_in[7];
  const float* b_hide   = (const float*)d_in[8];
  const float* W_out    = (const float*)d_in[9];
  const float* b_out    = (const float*)d_in[10];
  float* out = (float*)d_out;

  (void)d_ws; (void)ws_size;  // intentionally unused

  wt_transpose_kernel<<<24, 256, 0, stream>>>(W_hide);
  din_main_kernel<<<4096, 256, 0, stream>>>(qid_item, qid_cate, seq_item, seq_cate,
                                            mask, emb_item, emb_cate,
                                            b_hide, W_out, b_out, out);
}